// Round 1
// 3561.165 us; speedup vs baseline: 1.3545x; 1.3545x over previous
//
#include <hip/hip_runtime.h>
#include <cmath>

#define TSTEPS 256
#define DIM 1024
#define GST 35            // gate scratch col-stride

typedef _Float16 half8v __attribute__((ext_vector_type(8)));
typedef _Float16 half4v __attribute__((ext_vector_type(4)));
typedef float f32x4 __attribute__((ext_vector_type(4)));
typedef unsigned long long u64;

// ws layout:
//   xh  : [T][B][D] fp16 x (t-major), 16,777,216 halfs
//   h0r : [4 slot][64][1024] ring for h0
//   h1r : [4 slot][64][1024] ring for h1
//   cnts: leaf0[p][16 leaves, 16-word stride], leaf1[...] (131,072 uints)
// Phase p: cell0 computes h0[t=p] (reads x[p], h0[p-1]); cell1 computes
// h1[t=p-1] (reads h0[p-1], h1[p-2]). h[t] in ring slot t&3.
//
// R9 change (this round): h broadcast routed through per-XCD L2 instead of
// 6M/phase 8B agent loads hammering L3.
//   producer: pointwise -> hlds (LDS) -> wave0 does 128 coalesced 8B agent
//             stores (sc1, straight to L3), vmcnt(0), leaf add.
//   consumer: poll (relaxed, L3) -> ONE agent-scope ACQUIRE load (emits
//             buffer_inv: invalidates L1+L2) -> barrier -> plain cached
//             half8v loads of h. First toucher/line/XCD misses to L3, rest
//             hit L2. L3 h-read traffic/phase: 48MB -> ~2MB.
// The acquire covers ring-slot reuse AND cross-dispatch stale L2 lines
// (incl. p==0 read of prologue-zeroed slot 3 -> acquire runs at p==0 too).

__global__ void prologue(const float* __restrict__ x, _Float16* __restrict__ xh,
                         _Float16* __restrict__ hrings, unsigned* __restrict__ cnts)
{
    size_t gid  = (size_t)blockIdx.x * blockDim.x + threadIdx.x;
    size_t nthr = (size_t)gridDim.x * blockDim.x;
    for (size_t i = gid; i < 4194304u; i += nthr) {     // x[b][t][d4] -> xh[t][b][d]
        float4 v = ((const float4*)x)[i];
        half4v h = {(_Float16)v.x, (_Float16)v.y, (_Float16)v.z, (_Float16)v.w};
        unsigned d4 = (unsigned)i & 255u, t = ((unsigned)i >> 8) & 255u, b = (unsigned)i >> 16;
        ((half4v*)(xh + ((size_t)t * 64 + b) * 1024))[d4] = h;
    }
    for (size_t i = gid; i < 65536u; i += nthr) {       // zero both h rings
        half8v z = {};
        ((half8v*)hrings)[i] = z;
    }
    for (size_t i = gid; i < 139264u; i += nthr) cnts[i] = 0u;
}

// 256 blocks x 512 threads (8 waves). Blocks 0..127: cell0; 128..255: cell1.
// Block owns 32 gate-cols = 8 h-dims. Wave kq owns K-slice [kq*256,+256),
// weights in registers (16 x half8v). A held as A[4][8], loaded in one
// 32-load burst. Signal: 16 leaf counters/cell/phase (8 adds each, 64B
// apart). Wait: wave 0 lanes 0..31 poll all leaves of BOTH dep sets in
// parallel + ballot, s_sleep(16) pacing, latch satisfied lanes (R8 lesson:
// 256 pollers + s_sleep(1) on ONE root line oversubscribed it 4-8x).
__global__ __launch_bounds__(512, 2)
void lstm_persistent(const float* __restrict__ Wx0, const float* __restrict__ Wh0,
                     const float* __restrict__ b0,
                     const float* __restrict__ Wx1, const float* __restrict__ Wh1,
                     const float* __restrict__ b1,
                     const _Float16* __restrict__ xh, _Float16* __restrict__ h0r,
                     _Float16* __restrict__ h1r, unsigned* __restrict__ cnts,
                     float* __restrict__ out)
{
    extern __shared__ char smem[];
    _Float16* wfrag = (_Float16*)smem;          // 128 KB staging (dead after init)
    float*    gates = (float*)smem;             // [8 kq][64 m][GST] fp32, aliases
    _Float16* hlds  = (_Float16*)(smem + 102400); // [64][8] h gather (above gates' 71.7KB)

    const int tid  = threadIdx.x;
    const int blk  = blockIdx.x;
    const int cell = blk >> 7;
    const int wb   = blk & 127;
    const int lane = tid & 63, kq = tid >> 6;
    const int n15 = lane & 15, q = lane >> 4;

    unsigned* leaf0 = cnts;                     // [(p*16+leaf)*16]
    unsigned* leaf1 = cnts + 65536;
    unsigned* leafm = cell ? leaf1 : leaf0;

    // ---- one-time: weights -> LDS in B-fragment order (fp32->fp16) ----
    const float* m0 = cell ? Wx1 : Wx0;
    const float* m1 = cell ? Wh1 : Wh0;
    for (int idx = tid; idx < 16384; idx += 512) {
        int k = idx >> 3;
        int cc0 = (idx & 7) * 4;
        int g = cc0 >> 3, c = cc0 & 7;
        const float* src = (k < 1024 ? m0 + (size_t)k * 4096
                                     : m1 + (size_t)(k - 1024) * 4096)
                           + g * 1024 + wb * 8 + c;
        float4 v = *(const float4*)src;
        int skq = k >> 8, kt = (k >> 5) & 7, sq = (k >> 3) & 3, j = k & 7;
        float vv[4] = {v.x, v.y, v.z, v.w};
        #pragma unroll
        for (int e = 0; e < 4; ++e) {
            int cc = cc0 + e, nt = cc >> 4, nn = cc & 15;
            wfrag[((((skq * 2 + nt) * 8 + kt) * 64) + sq * 16 + nn) * 8 + j] = (_Float16)vv[e];
        }
    }
    __syncthreads();

    half8v wreg[16];                      // [nt*8 + kt]
    #pragma unroll
    for (int nt = 0; nt < 2; ++nt)
        #pragma unroll
        for (int kt = 0; kt < 8; ++kt)
            wreg[nt * 8 + kt] = *(const half8v*)
                &wfrag[((((kq * 2 + nt) * 8 + kt) * 64) + lane) * 8];
    __syncthreads();                      // wfrag dead; gates alias it

    const int pb = tid >> 3, pd = tid & 7;
    const float* bias = cell ? b1 : b0;
    const int gdim = wb * 8 + pd;
    const float bi = bias[0 * 1024 + gdim], bfg = bias[1 * 1024 + gdim],
                bg = bias[2 * 1024 + gdim], bo  = bias[3 * 1024 + gdim];
    float creg = 0.0f;

    const bool havex = (cell == 0) && (kq < 4);   // x-wave: plain cached loads

    for (int p = 0; p <= TSTEPS; ++p) {
        if (cell == 0 && p == TSTEPS) break;
        const bool active = cell ? (p >= 1) : true;

        half8v A[4][8];
        // x burst BEFORE the poll (no coherence needed; overlaps the wait)
        if (havex) {
            const _Float16* a = xh + (size_t)p * 65536 + (size_t)n15 * 1024
                                + kq * 256 + q * 8;
            #pragma unroll
            for (int mt = 0; mt < 4; ++mt)
                #pragma unroll
                for (int kt = 0; kt < 8; ++kt)
                    A[mt][kt] = *(const half8v*)(a + mt * 16384 + kt * 32);
        }

        // ---- wait for dependencies: wave 0, leaf-parallel + ballot ----
        if (tid < 64) {
            if (p >= 1) {
                // set A: leaf0[p-1] (lanes 0..15). set B (lanes 16..31):
                //   cell0: leaf1[p-3] (ring WAR), cell1: leaf1[p-1]
                const unsigned* addr = nullptr;
                if (tid < 16) {
                    addr = leaf0 + ((p - 1) * 16 + tid) * 16;
                } else if (tid < 32) {
                    int lf = tid - 16;
                    if (cell == 0) { if (p >= 3) addr = leaf1 + ((p - 3) * 16 + lf) * 16; }
                    else           { if (p >= 2) addr = leaf1 + ((p - 1) * 16 + lf) * 16; }
                }
                bool ok = (addr == nullptr);
                while (true) {
                    if (!ok)
                        ok = __hip_atomic_load(addr, __ATOMIC_RELAXED,
                                               __HIP_MEMORY_SCOPE_AGENT) >= 8u;
                    if (__ballot(ok) == ~0ull) break;
                    __builtin_amdgcn_s_sleep(16);
                }
            }
            // ACQUIRE: buffer_inv -> drop (possibly stale) L1/L2 h lines so the
            // plain cached loads below refetch current values from L3.
            unsigned dummy = __hip_atomic_load(leaf0, __ATOMIC_ACQUIRE,
                                               __HIP_MEMORY_SCOPE_AGENT);
            asm volatile("" :: "v"(dummy));
        }
        __syncthreads();

        // ---- h burst: plain cached loads (L2 dedups across the XCD) ----
        if (active && !havex) {
            const _Float16* arow;
            if (cell == 0) {
                arow = h0r + (size_t)((p - 1) & 3) * 65536 + (kq - 4) * 256;
            } else {
                arow = (kq < 4) ? h0r + (size_t)((p - 1) & 3) * 65536 + kq * 256
                                : h1r + (size_t)((p - 2) & 3) * 65536 + (kq - 4) * 256;
            }
            const _Float16* a = arow + (size_t)n15 * 1024 + q * 8;
            #pragma unroll
            for (int mt = 0; mt < 4; ++mt)
                #pragma unroll
                for (int kt = 0; kt < 8; ++kt)
                    A[mt][kt] = *(const half8v*)(a + mt * 16384 + kt * 32);
        }

        // ---- MFMA ----
        if (active) {
            #pragma unroll
            for (int mt = 0; mt < 4; ++mt) {
                f32x4 acc0 = {0.f, 0.f, 0.f, 0.f};
                f32x4 acc1 = {0.f, 0.f, 0.f, 0.f};
                #pragma unroll
                for (int kt = 0; kt < 8; ++kt) {
                    acc0 = __builtin_amdgcn_mfma_f32_16x16x32_f16(A[mt][kt], wreg[kt],     acc0, 0, 0, 0);
                    acc1 = __builtin_amdgcn_mfma_f32_16x16x32_f16(A[mt][kt], wreg[8 + kt], acc1, 0, 0, 0);
                }
                const int row0 = mt * 16 + q * 4;
                #pragma unroll
                for (int r = 0; r < 4; ++r) {
                    gates[(kq * 64 + row0 + r) * GST + n15]      = acc0[r];
                    gates[(kq * 64 + row0 + r) * GST + 16 + n15] = acc1[r];
                }
            }
        }
        __syncthreads();

        // ---- pointwise -> gather h into LDS ----
        if (active) {
            float g0 = 0.f, g1 = 0.f, g2 = 0.f, g3 = 0.f;
            #pragma unroll
            for (int k8 = 0; k8 < 8; ++k8) {
                const float* gsr = gates + (k8 * 64 + pb) * GST + pd;
                g0 += gsr[0]; g1 += gsr[8]; g2 += gsr[16]; g3 += gsr[24];
            }
            g0 += bi; g1 += bfg; g2 += bg; g3 += bo;
            float si = 1.f / (1.f + __expf(-g0));
            float sf = 1.f / (1.f + __expf(-g1));
            float so = 1.f / (1.f + __expf(-g3));
            float cn = sf * creg + si * tanhf(g2);
            float hn = so * tanhf(cn);
            creg = cn;
            hlds[pb * 8 + pd] = (_Float16)hn;
            if (cell && p == TSTEPS) out[pb * 1024 + gdim] = hn;
        }

        // ---- coalesced h store: wave 0, 2x8B agent stores per batch row ----
        if (active && p < TSTEPS) {
            __syncthreads();                          // hlds visible to wave 0
            if (tid < 64) {
                const u64* hp = (const u64*)(hlds + tid * 8);
                u64 lo = hp[0], hi = hp[1];
                _Float16* dst = cell ? (h1r + (size_t)((p - 1) & 3) * 65536)
                                     : (h0r + (size_t)(p & 3) * 65536);
                u64* dp = (u64*)(dst + (size_t)tid * 1024 + wb * 8);
                __hip_atomic_store(dp,     lo, __ATOMIC_RELAXED, __HIP_MEMORY_SCOPE_AGENT);
                __hip_atomic_store(dp + 1, hi, __ATOMIC_RELAXED, __HIP_MEMORY_SCOPE_AGENT);
            }
        }

        // ---- signal: one leaf add per block (8 blocks/leaf, 64B apart) ----
        if (p < TSTEPS) {
            if (tid < 64)
                asm volatile("s_waitcnt vmcnt(0)" ::: "memory");   // h stores at L3
            __syncthreads();
            if (tid == 0)
                __hip_atomic_fetch_add(leafm + (p * 16 + (wb >> 3)) * 16, 1u,
                                       __ATOMIC_RELAXED, __HIP_MEMORY_SCOPE_AGENT);
        }
    }
}

extern "C" void kernel_launch(void* const* d_in, const int* in_sizes, int n_in,
                              void* d_out, int out_size, void* d_ws, size_t ws_size,
                              hipStream_t stream)
{
    const float* x   = (const float*)d_in[0];
    const float* Wx0 = (const float*)d_in[1];
    const float* Wh0 = (const float*)d_in[2];
    const float* b0  = (const float*)d_in[3];
    const float* Wx1 = (const float*)d_in[4];
    const float* Wh1 = (const float*)d_in[5];
    const float* b1  = (const float*)d_in[6];
    float* out = (float*)d_out;

    _Float16* xh   = (_Float16*)d_ws;
    _Float16* h0r  = xh + (size_t)16777216;
    _Float16* h1r  = h0r + 262144;
    unsigned* cnts = (unsigned*)(h1r + 262144);

    hipLaunchKernelGGL(prologue, dim3(2048), dim3(256), 0, stream, x, xh, h0r, cnts);

    size_t smem = 131072;
    (void)hipFuncSetAttribute((const void*)lstm_persistent,
                              hipFuncAttributeMaxDynamicSharedMemorySize, (int)smem);

    void* args[] = {(void*)&Wx0, (void*)&Wh0, (void*)&b0,
                    (void*)&Wx1, (void*)&Wh1, (void*)&b1,
                    (void*)&xh, (void*)&h0r, (void*)&h1r,
                    (void*)&cnts, (void*)&out};
    (void)hipLaunchCooperativeKernel((const void*)lstm_persistent, dim3(256), dim3(512),
                                     args, (unsigned)smem, stream);
}

// Round 2
// 3420.143 us; speedup vs baseline: 1.4104x; 1.0412x over previous
//
#include <hip/hip_runtime.h>
#include <cmath>

#define TSTEPS 256
#define DIM 1024
#define GST 35            // gate scratch col-stride

typedef _Float16 half8v __attribute__((ext_vector_type(8)));
typedef _Float16 half4v __attribute__((ext_vector_type(4)));
typedef float f32x4 __attribute__((ext_vector_type(4)));
typedef unsigned long long u64;

// ws layout:
//   xh  : [T][B][D] fp16 x (t-major), 16,777,216 halfs
//   h0r : [4 slot][64][1024] ring for h0
//   h1r : [4 slot][64][1024] ring for h1
//   cnts: leaf0[p][16 leaves, 16-word stride], leaf1[...] (131,072 uints)
// Phase p: cell0 computes h0[t=p] (reads x[p], h0[p-1]); cell1 computes
// h1[t=p-1] (reads h0[p-1], h1[p-2]). h[t] in ring slot t&3.
//
// R9: h broadcast through per-XCD L2 (producer: coalesced 8B agent stores;
//     consumer: agent-acquire invalidate, then plain cached half8v loads).
// R10 (this round): shave serial latency at ~710MHz effective clock:
//   - acquire-LOAD replaced by __builtin_amdgcn_fence(ACQUIRE, agent):
//     same buffer_inv, no dependent L3 round trip.
//   - leaf signal fired by tid0 right after wave0's own vmcnt(0) — deletes
//     the trailing __syncthreads from the signal path (gates/hlds WAR still
//     fenced by pre-gather barrier + next phase's post-poll barrier).
//   - poll pacing s_sleep(16) -> s_sleep(4): detect quantum 1024->256cy.
//     Safe vs R8 lesson: polls spread over 32 distinct 64B lines.

__global__ void prologue(const float* __restrict__ x, _Float16* __restrict__ xh,
                         _Float16* __restrict__ hrings, unsigned* __restrict__ cnts)
{
    size_t gid  = (size_t)blockIdx.x * blockDim.x + threadIdx.x;
    size_t nthr = (size_t)gridDim.x * blockDim.x;
    for (size_t i = gid; i < 4194304u; i += nthr) {     // x[b][t][d4] -> xh[t][b][d]
        float4 v = ((const float4*)x)[i];
        half4v h = {(_Float16)v.x, (_Float16)v.y, (_Float16)v.z, (_Float16)v.w};
        unsigned d4 = (unsigned)i & 255u, t = ((unsigned)i >> 8) & 255u, b = (unsigned)i >> 16;
        ((half4v*)(xh + ((size_t)t * 64 + b) * 1024))[d4] = h;
    }
    for (size_t i = gid; i < 65536u; i += nthr) {       // zero both h rings
        half8v z = {};
        ((half8v*)hrings)[i] = z;
    }
    for (size_t i = gid; i < 139264u; i += nthr) cnts[i] = 0u;
}

// 256 blocks x 512 threads (8 waves). Blocks 0..127: cell0; 128..255: cell1.
// Block owns 32 gate-cols = 8 h-dims. Wave kq owns K-slice [kq*256,+256),
// weights in registers (16 x half8v). A held as A[4][8], loaded in one
// 32-load burst. Signal: 16 leaf counters/cell/phase (8 adds each, 64B
// apart). Wait: wave 0 lanes 0..31 poll all leaves of BOTH dep sets in
// parallel + ballot, latch satisfied lanes.
__global__ __launch_bounds__(512, 2)
void lstm_persistent(const float* __restrict__ Wx0, const float* __restrict__ Wh0,
                     const float* __restrict__ b0,
                     const float* __restrict__ Wx1, const float* __restrict__ Wh1,
                     const float* __restrict__ b1,
                     const _Float16* __restrict__ xh, _Float16* __restrict__ h0r,
                     _Float16* __restrict__ h1r, unsigned* __restrict__ cnts,
                     float* __restrict__ out)
{
    extern __shared__ char smem[];
    _Float16* wfrag = (_Float16*)smem;          // 128 KB staging (dead after init)
    float*    gates = (float*)smem;             // [8 kq][64 m][GST] fp32, aliases
    _Float16* hlds  = (_Float16*)(smem + 102400); // [64][8] h gather (above gates' 71.7KB)

    const int tid  = threadIdx.x;
    const int blk  = blockIdx.x;
    const int cell = blk >> 7;
    const int wb   = blk & 127;
    const int lane = tid & 63, kq = tid >> 6;
    const int n15 = lane & 15, q = lane >> 4;

    unsigned* leaf0 = cnts;                     // [(p*16+leaf)*16]
    unsigned* leaf1 = cnts + 65536;
    unsigned* leafm = cell ? leaf1 : leaf0;

    // ---- one-time: weights -> LDS in B-fragment order (fp32->fp16) ----
    const float* m0 = cell ? Wx1 : Wx0;
    const float* m1 = cell ? Wh1 : Wh0;
    for (int idx = tid; idx < 16384; idx += 512) {
        int k = idx >> 3;
        int cc0 = (idx & 7) * 4;
        int g = cc0 >> 3, c = cc0 & 7;
        const float* src = (k < 1024 ? m0 + (size_t)k * 4096
                                     : m1 + (size_t)(k - 1024) * 4096)
                           + g * 1024 + wb * 8 + c;
        float4 v = *(const float4*)src;
        int skq = k >> 8, kt = (k >> 5) & 7, sq = (k >> 3) & 3, j = k & 7;
        float vv[4] = {v.x, v.y, v.z, v.w};
        #pragma unroll
        for (int e = 0; e < 4; ++e) {
            int cc = cc0 + e, nt = cc >> 4, nn = cc & 15;
            wfrag[((((skq * 2 + nt) * 8 + kt) * 64) + sq * 16 + nn) * 8 + j] = (_Float16)vv[e];
        }
    }
    __syncthreads();

    half8v wreg[16];                      // [nt*8 + kt]
    #pragma unroll
    for (int nt = 0; nt < 2; ++nt)
        #pragma unroll
        for (int kt = 0; kt < 8; ++kt)
            wreg[nt * 8 + kt] = *(const half8v*)
                &wfrag[((((kq * 2 + nt) * 8 + kt) * 64) + lane) * 8];
    __syncthreads();                      // wfrag dead; gates alias it

    const int pb = tid >> 3, pd = tid & 7;
    const float* bias = cell ? b1 : b0;
    const int gdim = wb * 8 + pd;
    const float bi = bias[0 * 1024 + gdim], bfg = bias[1 * 1024 + gdim],
                bg = bias[2 * 1024 + gdim], bo  = bias[3 * 1024 + gdim];
    float creg = 0.0f;

    const bool havex = (cell == 0) && (kq < 4);   // x-wave: plain cached loads

    for (int p = 0; p <= TSTEPS; ++p) {
        if (cell == 0 && p == TSTEPS) break;
        const bool active = cell ? (p >= 1) : true;

        half8v A[4][8];
        // x burst BEFORE the poll (no coherence needed; overlaps the wait)
        if (havex) {
            const _Float16* a = xh + (size_t)p * 65536 + (size_t)n15 * 1024
                                + kq * 256 + q * 8;
            #pragma unroll
            for (int mt = 0; mt < 4; ++mt)
                #pragma unroll
                for (int kt = 0; kt < 8; ++kt)
                    A[mt][kt] = *(const half8v*)(a + mt * 16384 + kt * 32);
        }

        // ---- wait for dependencies: wave 0, leaf-parallel + ballot ----
        if (tid < 64) {
            if (p >= 1) {
                // set A: leaf0[p-1] (lanes 0..15). set B (lanes 16..31):
                //   cell0: leaf1[p-3] (ring WAR), cell1: leaf1[p-1]
                const unsigned* addr = nullptr;
                if (tid < 16) {
                    addr = leaf0 + ((p - 1) * 16 + tid) * 16;
                } else if (tid < 32) {
                    int lf = tid - 16;
                    if (cell == 0) { if (p >= 3) addr = leaf1 + ((p - 3) * 16 + lf) * 16; }
                    else           { if (p >= 2) addr = leaf1 + ((p - 1) * 16 + lf) * 16; }
                }
                bool ok = (addr == nullptr);
                while (true) {
                    if (!ok)
                        ok = __hip_atomic_load(addr, __ATOMIC_RELAXED,
                                               __HIP_MEMORY_SCOPE_AGENT) >= 8u;
                    if (__ballot(ok) == ~0ull) break;
                    __builtin_amdgcn_s_sleep(4);
                }
            }
            // ACQUIRE fence: buffer_inv (no dependent load) -> drop possibly
            // stale L1/L2 h lines; plain cached loads below refetch from L3.
            __builtin_amdgcn_fence(__ATOMIC_ACQUIRE, "agent");
        }
        __syncthreads();

        // ---- h burst: plain cached loads (L2 dedups across the XCD) ----
        if (active && !havex) {
            const _Float16* arow;
            if (cell == 0) {
                arow = h0r + (size_t)((p - 1) & 3) * 65536 + (kq - 4) * 256;
            } else {
                arow = (kq < 4) ? h0r + (size_t)((p - 1) & 3) * 65536 + kq * 256
                                : h1r + (size_t)((p - 2) & 3) * 65536 + (kq - 4) * 256;
            }
            const _Float16* a = arow + (size_t)n15 * 1024 + q * 8;
            #pragma unroll
            for (int mt = 0; mt < 4; ++mt)
                #pragma unroll
                for (int kt = 0; kt < 8; ++kt)
                    A[mt][kt] = *(const half8v*)(a + mt * 16384 + kt * 32);
        }

        // ---- MFMA ----
        if (active) {
            #pragma unroll
            for (int mt = 0; mt < 4; ++mt) {
                f32x4 acc0 = {0.f, 0.f, 0.f, 0.f};
                f32x4 acc1 = {0.f, 0.f, 0.f, 0.f};
                #pragma unroll
                for (int kt = 0; kt < 8; ++kt) {
                    acc0 = __builtin_amdgcn_mfma_f32_16x16x32_f16(A[mt][kt], wreg[kt],     acc0, 0, 0, 0);
                    acc1 = __builtin_amdgcn_mfma_f32_16x16x32_f16(A[mt][kt], wreg[8 + kt], acc1, 0, 0, 0);
                }
                const int row0 = mt * 16 + q * 4;
                #pragma unroll
                for (int r = 0; r < 4; ++r) {
                    gates[(kq * 64 + row0 + r) * GST + n15]      = acc0[r];
                    gates[(kq * 64 + row0 + r) * GST + 16 + n15] = acc1[r];
                }
            }
        }
        __syncthreads();

        // ---- pointwise -> gather h into LDS ----
        if (active) {
            float g0 = 0.f, g1 = 0.f, g2 = 0.f, g3 = 0.f;
            #pragma unroll
            for (int k8 = 0; k8 < 8; ++k8) {
                const float* gsr = gates + (k8 * 64 + pb) * GST + pd;
                g0 += gsr[0]; g1 += gsr[8]; g2 += gsr[16]; g3 += gsr[24];
            }
            g0 += bi; g1 += bfg; g2 += bg; g3 += bo;
            float si = 1.f / (1.f + __expf(-g0));
            float sf = 1.f / (1.f + __expf(-g1));
            float so = 1.f / (1.f + __expf(-g3));
            float cn = sf * creg + si * tanhf(g2);
            float hn = so * tanhf(cn);
            creg = cn;
            hlds[pb * 8 + pd] = (_Float16)hn;
            if (cell && p == TSTEPS) out[pb * 1024 + gdim] = hn;
        }

        // ---- h store + signal: wave 0 only; tid0 adds right after vmcnt(0)
        //      (no trailing barrier on the signal path) ----
        if (p < TSTEPS) {
            if (active) __syncthreads();              // hlds visible to wave 0
            if (tid < 64) {
                if (active) {
                    const u64* hp = (const u64*)(hlds + tid * 8);
                    u64 lo = hp[0], hi = hp[1];
                    _Float16* dst = cell ? (h1r + (size_t)((p - 1) & 3) * 65536)
                                         : (h0r + (size_t)(p & 3) * 65536);
                    u64* dp = (u64*)(dst + (size_t)tid * 1024 + wb * 8);
                    __hip_atomic_store(dp,     lo, __ATOMIC_RELAXED, __HIP_MEMORY_SCOPE_AGENT);
                    __hip_atomic_store(dp + 1, hi, __ATOMIC_RELAXED, __HIP_MEMORY_SCOPE_AGENT);
                    asm volatile("s_waitcnt vmcnt(0)" ::: "memory");   // h at L3
                }
                if (tid == 0)
                    __hip_atomic_fetch_add(leafm + (p * 16 + (wb >> 3)) * 16, 1u,
                                           __ATOMIC_RELAXED, __HIP_MEMORY_SCOPE_AGENT);
            }
        }
    }
}

extern "C" void kernel_launch(void* const* d_in, const int* in_sizes, int n_in,
                              void* d_out, int out_size, void* d_ws, size_t ws_size,
                              hipStream_t stream)
{
    const float* x   = (const float*)d_in[0];
    const float* Wx0 = (const float*)d_in[1];
    const float* Wh0 = (const float*)d_in[2];
    const float* b0  = (const float*)d_in[3];
    const float* Wx1 = (const float*)d_in[4];
    const float* Wh1 = (const float*)d_in[5];
    const float* b1  = (const float*)d_in[6];
    float* out = (float*)d_out;

    _Float16* xh   = (_Float16*)d_ws;
    _Float16* h0r  = xh + (size_t)16777216;
    _Float16* h1r  = h0r + 262144;
    unsigned* cnts = (unsigned*)(h1r + 262144);

    hipLaunchKernelGGL(prologue, dim3(2048), dim3(256), 0, stream, x, xh, h0r, cnts);

    size_t smem = 131072;
    (void)hipFuncSetAttribute((const void*)lstm_persistent,
                              hipFuncAttributeMaxDynamicSharedMemorySize, (int)smem);

    void* args[] = {(void*)&Wx0, (void*)&Wh0, (void*)&b0,
                    (void*)&Wx1, (void*)&Wh1, (void*)&b1,
                    (void*)&xh, (void*)&h0r, (void*)&h1r,
                    (void*)&cnts, (void*)&out};
    (void)hipLaunchCooperativeKernel((const void*)lstm_persistent, dim3(256), dim3(512),
                                     args, (unsigned)smem, stream);
}